// Round 8
// baseline (216.915 us; speedup 1.0000x reference)
//
#include <hip/hip_runtime.h>
#include <hip/hip_bf16.h>

typedef __attribute__((ext_vector_type(8))) short short8;
typedef __attribute__((ext_vector_type(4))) float f32x4;
typedef __attribute__((ext_vector_type(2))) float f32x2;
typedef __attribute__((ext_vector_type(16))) float f32x16;
typedef __attribute__((ext_vector_type(4))) unsigned short u16x4;
typedef __attribute__((ext_vector_type(8))) unsigned short u16x8;

#define M_TOT 16384
#define N_TOT 2048
#define K_TOT 2048

__device__ __forceinline__ unsigned short f2bf(float f) {
  unsigned u = __builtin_bit_cast(unsigned, f);
  u += 0x7FFFu + ((u >> 16) & 1u);   // RNE
  return (unsigned short)(u >> 16);
}
__device__ __forceinline__ float bf2f(unsigned short h) {
  return __builtin_bit_cast(float, (unsigned)h << 16);
}

// ===================== TILED FAST PATH ======================================
// Single-product scheme (R6-verified numerics, absmax 0.25):
//   out = x_hi @ bf16(W_base)^T + bias + T[m,:]·CU[n,:]
// ws: Whi_t[4M ush] Xhi_t[32M ush] T[32768 f32] CU[4096 f32]
// NEW tiling for the 8-phase GEMM (BM=BN=256, BK=64):
//   W tiles: [N/256=8][K/64=32] x [256 rows][64 k] bf16 = 32KB, swizzled
//   X tiles: [M/256=64][K/64=32] x 32KB, swizzled
// swizzle: inner byte = row*128 + ((chunk ^ (row&7)) << 4), chunk = 16B (8 k)

__global__ void wsplit_base(const float* __restrict__ Wb, const float* __restrict__ U,
                            const float* __restrict__ S, const float* __restrict__ Vh,
                            const float* __restrict__ P, const float* __restrict__ gv,
                            unsigned short* __restrict__ Whi_t, float* __restrict__ CU) {
  float c0 = 0.f, c1 = 0.f;
#pragma unroll
  for (int u = 0; u < 16; ++u) { c0 += gv[u] * P[2 * u]; c1 += gv[u] * P[2 * u + 1]; }
  c0 *= S[0]; c1 *= S[1];
  int t = blockIdx.x * 256 + threadIdx.x;
  int o = t >> 8;            // W row (n) 0..2047
  int c = t & 255;           // 16B chunk (8 k-elems), k = c*8
  int k = c << 3;
  f32x4 wb0 = *(const f32x4*)(Wb + (size_t)o * K_TOT + k);
  f32x4 wb1 = *(const f32x4*)(Wb + (size_t)o * K_TOT + k + 4);
  u16x8 hi;
#pragma unroll
  for (int q = 0; q < 4; ++q) hi[q] = f2bf(wb0[q]);
#pragma unroll
  for (int q = 0; q < 4; ++q) hi[4 + q] = f2bf(wb1[q]);
  int kt = c >> 3, cc = c & 7;
  size_t base = (size_t)((o >> 8) * 32 + kt) * 32768;              // bytes
  int inner = ((o & 255) << 7) + (((cc ^ (o & 7))) << 4);
  *(u16x8*)((char*)Whi_t + base + inner) = hi;
  if (c == 0) {
    CU[2 * o]     = c0 * U[2 * o];
    CU[2 * o + 1] = c1 * U[2 * o + 1];
  }
}

// x -> bf16 hi tiles (256x64 swizzled);  T[m][r] = sum_k x[m,k]*Vh[r,k]
__global__ void xsplit_tiled(const float* __restrict__ X, const float* __restrict__ Vh,
                             unsigned short* __restrict__ Xhi_t, float* __restrict__ T) {
  int w = threadIdx.x >> 6, lane = threadIdx.x & 63;
  int m = blockIdx.x * 4 + w;
  const float* xr = X + (size_t)m * K_TOT;
  float t0 = 0.f, t1 = 0.f;
#pragma unroll
  for (int p = 0; p < 4; ++p) {
    int c = lane + (p << 6);   // chunk 0..255
    int k = c << 3;
    f32x4 x0 = *(const f32x4*)(xr + k);
    f32x4 x1 = *(const f32x4*)(xr + k + 4);
    f32x4 v0a = *(const f32x4*)(Vh + k);
    f32x4 v0b = *(const f32x4*)(Vh + k + 4);
    f32x4 v1a = *(const f32x4*)(Vh + K_TOT + k);
    f32x4 v1b = *(const f32x4*)(Vh + K_TOT + k + 4);
    u16x8 hi;
#pragma unroll
    for (int q = 0; q < 4; ++q) {
      hi[q] = f2bf(x0[q]);
      t0 += x0[q] * v0a[q]; t1 += x0[q] * v1a[q];
    }
#pragma unroll
    for (int q = 0; q < 4; ++q) {
      hi[4 + q] = f2bf(x1[q]);
      t0 += x1[q] * v0b[q]; t1 += x1[q] * v1b[q];
    }
    size_t base = (size_t)((m >> 8) * 32 + (c >> 3)) * 32768;      // bytes
    int inner = ((m & 255) << 7) + ((((c & 7) ^ (m & 7))) << 4);
    *(u16x8*)((char*)Xhi_t + base + inner) = hi;
  }
#pragma unroll
  for (int d = 32; d; d >>= 1) {
    t0 += __shfl_xor(t0, d, 64);
    t1 += __shfl_xor(t1, d, 64);
  }
  if (lane == 0) { T[2 * m] = t0; T[2 * m + 1] = t1; }
}

// 8-phase-style GEMM: 32x32x16 MFMA, BM=256 BN=256 BK=64, 8 waves (2Mx4N),
// wave tile 128x64, acc[4][2]. 4 phases per K-tile (one per ks), dbuf LDS
// (128KB), counted vmcnt(4) once per tile, setprio around MFMA clusters.
__global__ __launch_bounds__(512, 2) void gemm8_kernel(
    const unsigned short* __restrict__ Xhi_t, const unsigned short* __restrict__ Whi_t,
    const float* __restrict__ bias, const float* __restrict__ T,
    const float* __restrict__ CU, float* __restrict__ out) {
  __shared__ unsigned short sA[2][16384];   // 2 x 32KB swizzled A
  __shared__ unsigned short sB[2][16384];   // 2 x 32KB swizzled B

  const int tid = threadIdx.x, lane = tid & 63, w = tid >> 6;
  const int wr = w >> 2, wc = w & 3;        // 2M x 4N wave grid
  const int l31 = lane & 31, g = (lane >> 5) & 1;

  // bijective XCD swizzle: 512 blocks, 512%8==0
  const int bid = blockIdx.x;
  const int nb = ((bid & 7) << 6) | (bid >> 3);
  const int bn = nb & 7, bm = nb >> 3;

  f32x16 acc[4][2] = {};

  const unsigned short* At = Xhi_t + (size_t)((bm << 5)) * 16384;  // [bm][kt] tiles
  const unsigned short* Bt = Whi_t + (size_t)((bn << 5)) * 16384;

  // stage: per thread 4 A-chunks + 4 B-chunks of 16B per tile (2048 chunks each)
#define GLDS(src, dst) __builtin_amdgcn_global_load_lds(                         \
      (const __attribute__((address_space(1))) void*)(src),                      \
      (__attribute__((address_space(3))) void*)(dst), 16, 0, 0)

#define STG8(bufi, kt_, base_) do {                                              \
    int ch0 = tid + (base_);                                                     \
    int ch1 = ch0 + 512;                                                         \
    const unsigned short* a_s = At + (size_t)(kt_) * 16384;                      \
    const unsigned short* b_s = Bt + (size_t)(kt_) * 16384;                      \
    GLDS(a_s + ch0 * 8, &sA[bufi][ch0 * 8]);                                     \
    GLDS(a_s + ch1 * 8, &sA[bufi][ch1 * 8]);                                     \
    GLDS(b_s + ch0 * 8, &sB[bufi][ch0 * 8]);                                     \
    GLDS(b_s + ch1 * 8, &sB[bufi][ch1 * 8]);                                     \
  } while (0)

  // fragment swizzled byte offsets; ks folds in via XOR of bits 5-6
  int aoff[4], boff[2];
#pragma unroll
  for (int i = 0; i < 4; ++i) {
    int row = (wr << 7) + (i << 5) + l31;
    aoff[i] = (row << 7) + ((g ^ (row & 7)) << 4);
  }
#pragma unroll
  for (int j = 0; j < 2; ++j) {
    int row = (wc << 6) + (j << 5) + l31;
    boff[j] = (row << 7) + ((g ^ (row & 7)) << 4);
  }

#define PHASE8(ks_) do {                                                         \
    const int kx = (ks_) << 5;                                                   \
    short8 a0 = *(const short8*)(pA + (aoff[0] ^ kx));                           \
    short8 a1 = *(const short8*)(pA + (aoff[1] ^ kx));                           \
    short8 a2 = *(const short8*)(pA + (aoff[2] ^ kx));                           \
    short8 a3 = *(const short8*)(pA + (aoff[3] ^ kx));                           \
    short8 b0 = *(const short8*)(pB + (boff[0] ^ kx));                           \
    short8 b1 = *(const short8*)(pB + (boff[1] ^ kx));                           \
    __builtin_amdgcn_s_setprio(1);                                               \
    acc[0][0] = __builtin_amdgcn_mfma_f32_32x32x16_bf16(a0, b0, acc[0][0], 0, 0, 0); \
    acc[0][1] = __builtin_amdgcn_mfma_f32_32x32x16_bf16(a0, b1, acc[0][1], 0, 0, 0); \
    acc[1][0] = __builtin_amdgcn_mfma_f32_32x32x16_bf16(a1, b0, acc[1][0], 0, 0, 0); \
    acc[1][1] = __builtin_amdgcn_mfma_f32_32x32x16_bf16(a1, b1, acc[1][1], 0, 0, 0); \
    acc[2][0] = __builtin_amdgcn_mfma_f32_32x32x16_bf16(a2, b0, acc[2][0], 0, 0, 0); \
    acc[2][1] = __builtin_amdgcn_mfma_f32_32x32x16_bf16(a2, b1, acc[2][1], 0, 0, 0); \
    acc[3][0] = __builtin_amdgcn_mfma_f32_32x32x16_bf16(a3, b0, acc[3][0], 0, 0, 0); \
    acc[3][1] = __builtin_amdgcn_mfma_f32_32x32x16_bf16(a3, b1, acc[3][1], 0, 0, 0); \
    __builtin_amdgcn_s_setprio(0);                                               \
  } while (0)

  // prologue: fully stage tile 0 into buf 0
  STG8(0, 0, 0);
  STG8(0, 0, 1024);

  for (int kt = 0; kt < 32; ++kt) {
    const int cur = kt & 1;
    const char* pA = (const char*)&sA[cur][0];
    const char* pB = (const char*)&sB[cur][0];

    // ---- phase 0: issue 4 stage loads (kt+1), counted wait, barrier, compute
    if (kt < 31) {
      STG8(cur ^ 1, kt + 1, 0);
      asm volatile("s_waitcnt vmcnt(4)" ::: "memory");   // tile kt fully landed
    } else {
      asm volatile("s_waitcnt vmcnt(0)" ::: "memory");
    }
    __builtin_amdgcn_sched_barrier(0);
    __builtin_amdgcn_s_barrier();        // all waves: buf[cur] staged
    __builtin_amdgcn_sched_barrier(0);
    PHASE8(0);
    __builtin_amdgcn_sched_barrier(0);
    __builtin_amdgcn_s_barrier();
    __builtin_amdgcn_sched_barrier(0);

    // ---- phase 1: issue remaining 4 stage loads (kt+1), compute ks=1
    if (kt < 31) STG8(cur ^ 1, kt + 1, 1024);
    PHASE8(1);
    __builtin_amdgcn_sched_barrier(0);
    __builtin_amdgcn_s_barrier();
    __builtin_amdgcn_sched_barrier(0);

    // ---- phase 2
    PHASE8(2);
    __builtin_amdgcn_sched_barrier(0);
    __builtin_amdgcn_s_barrier();
    __builtin_amdgcn_sched_barrier(0);

    // ---- phase 3 (last reads of buf[cur]; barrier gates next-tile restage)
    PHASE8(3);
    __builtin_amdgcn_sched_barrier(0);
    __builtin_amdgcn_s_barrier();
    __builtin_amdgcn_sched_barrier(0);
  }

  // epilogue: 32x32 C/D map col=lane&31, row=(reg&3)+8*(reg>>2)+4*(lane>>5)
  float bv[2], cu0[2], cu1[2];
  int nn[2];
#pragma unroll
  for (int j = 0; j < 2; ++j) {
    int n = (bn << 8) + (wc << 6) + (j << 5) + l31;
    nn[j] = n;
    bv[j] = bias[n];
    f32x2 cu = *(const f32x2*)(CU + 2 * n);
    cu0[j] = cu.x; cu1[j] = cu.y;
  }
#pragma unroll
  for (int i = 0; i < 4; ++i) {
    const int mb = (bm << 8) + (wr << 7) + (i << 5) + (g << 2);
#pragma unroll
    for (int q = 0; q < 16; ++q) {
      int m = mb + (q & 3) + ((q >> 2) << 3);
      f32x2 tv = *(const f32x2*)(T + 2 * m);
      float* orow = out + (size_t)m * N_TOT;
#pragma unroll
      for (int j = 0; j < 2; ++j)
        orow[nn[j]] = acc[i][j][q] + bv[j] + tv.x * cu0[j] + tv.y * cu1[j];
    }
  }
}

// ===================== FALLBACK PATH (round-1, proven) ======================
__global__ void wsplit_kernel(const float* __restrict__ Wb, const float* __restrict__ U,
                              const float* __restrict__ S, const float* __restrict__ Vh,
                              const float* __restrict__ P, const float* __restrict__ gv,
                              unsigned short* __restrict__ Whi, unsigned short* __restrict__ Wlo) {
  float c0 = 0.f, c1 = 0.f;
#pragma unroll
  for (int u = 0; u < 16; ++u) { c0 += gv[u] * P[2 * u]; c1 += gv[u] * P[2 * u + 1]; }
  c0 *= S[0]; c1 *= S[1];
  int t = blockIdx.x * 256 + threadIdx.x;
  int o = t >> 9;
  int d = (t & 511) << 2;
  f32x4 wb = *(const f32x4*)(Wb + (size_t)o * K_TOT + d);
  f32x4 v0 = *(const f32x4*)(Vh + d);
  f32x4 v1 = *(const f32x4*)(Vh + K_TOT + d);
  float u0 = U[2 * o] * c0, u1 = U[2 * o + 1] * c1;
  u16x4 hi, lo;
#pragma unroll
  for (int q = 0; q < 4; ++q) {
    float w = wb[q] + u0 * v0[q] + u1 * v1[q];
    unsigned short h = f2bf(w);
    hi[q] = h;
    lo[q] = f2bf(w - bf2f(h));
  }
  *(u16x4*)(Whi + (size_t)o * K_TOT + d) = hi;
  *(u16x4*)(Wlo + (size_t)o * K_TOT + d) = lo;
}

__global__ __launch_bounds__(256) void gemm_split_kernel(
    const float* __restrict__ X, const unsigned short* __restrict__ Whi,
    const unsigned short* __restrict__ Wlo, const float* __restrict__ bias,
    float* __restrict__ out) {
  __shared__ unsigned short sAhi[128 * 32];
  __shared__ unsigned short sAlo[128 * 32];
  __shared__ unsigned short sBhi[128 * 32];
  __shared__ unsigned short sBlo[128 * 32];
  const int tid = threadIdx.x;
  const int lane = tid & 63;
  const int w = tid >> 6;
  const int wr = w >> 1, wc = w & 1;
  const int r = lane & 15, g = lane >> 4;
  const int bn = blockIdx.x, bm = blockIdx.y;
  f32x4 acc[4][4] = {};
  const int arow = tid >> 3;
  const int acol = (tid & 7) << 2;
  const float* Abase = X + (size_t)(bm * 128 + arow) * K_TOT + acol;
  const int brow = lane >> 2;
  const int bcol = (lane & 3) << 3;
  const size_t bgoff = (size_t)(bn * 128 + brow) * K_TOT + bcol;
  for (int kt = 0; kt < K_TOT / 32; ++kt) {
    f32x4 av[4];
#pragma unroll
    for (int p = 0; p < 4; ++p)
      av[p] = *(const f32x4*)(Abase + (size_t)(p * 32) * K_TOT + kt * 32);
    __syncthreads();
#pragma unroll
    for (int ii = 0; ii < 2; ++ii) {
      int chunk = w * 2 + ii;
      size_t go = bgoff + (size_t)(chunk * 16) * K_TOT + kt * 32;
      __builtin_amdgcn_global_load_lds(
          (const __attribute__((address_space(1))) void*)(Whi + go),
          (__attribute__((address_space(3))) void*)(&sBhi[chunk * 512]), 16, 0, 0);
      __builtin_amdgcn_global_load_lds(
          (const __attribute__((address_space(1))) void*)(Wlo + go),
          (__attribute__((address_space(3))) void*)(&sBlo[chunk * 512]), 16, 0, 0);
    }
#pragma unroll
    for (int p = 0; p < 4; ++p) {
      u16x4 hi, lo;
#pragma unroll
      for (int q = 0; q < 4; ++q) {
        float f = av[p][q];
        unsigned short h = f2bf(f);
        hi[q] = h;
        lo[q] = f2bf(f - bf2f(h));
      }
      int off = (arow + p * 32) * 32 + acol;
      *(u16x4*)&sAhi[off] = hi;
      *(u16x4*)&sAlo[off] = lo;
    }
    __syncthreads();
    short8 ah[4], al[4], bh[4], bl[4];
#pragma unroll
    for (int i = 0; i < 4; ++i) {
      int off = (wr * 64 + i * 16 + r) * 32 + g * 8;
      ah[i] = *(const short8*)&sAhi[off];
      al[i] = *(const short8*)&sAlo[off];
    }
#pragma unroll
    for (int j = 0; j < 4; ++j) {
      int off = (wc * 64 + j * 16 + r) * 32 + g * 8;
      bh[j] = *(const short8*)&sBhi[off];
      bl[j] = *(const short8*)&sBlo[off];
    }
#pragma unroll
    for (int i = 0; i < 4; ++i)
#pragma unroll
      for (int j = 0; j < 4; ++j) {
        acc[i][j] = __builtin_amdgcn_mfma_f32_16x16x32_bf16(ah[i], bh[j], acc[i][j], 0, 0, 0);
        acc[i][j] = __builtin_amdgcn_mfma_f32_16x16x32_bf16(ah[i], bl[j], acc[i][j], 0, 0, 0);
        acc[i][j] = __builtin_amdgcn_mfma_f32_16x16x32_bf16(al[i], bh[j], acc[i][j], 0, 0, 0);
      }
  }
#pragma unroll
  for (int j = 0; j < 4; ++j) {
    int n = bn * 128 + wc * 64 + j * 16 + r;
    float bvv = bias[n];
#pragma unroll
    for (int i = 0; i < 4; ++i) {
      int mbase = bm * 128 + wr * 64 + i * 16 + g * 4;
#pragma unroll
      for (int q = 0; q < 4; ++q) {
        out[(size_t)(mbase + q) * N_TOT + n] = acc[i][j][q] + bvv;
      }
    }
  }
}

// ===========================================================================
extern "C" void kernel_launch(void* const* d_in, const int* in_sizes, int n_in,
                              void* d_out, int out_size, void* d_ws, size_t ws_size,
                              hipStream_t stream) {
  const float* x    = (const float*)d_in[0];
  const float* Wb   = (const float*)d_in[1];
  const float* bias = (const float*)d_in[2];
  const float* U    = (const float*)d_in[3];
  const float* S    = (const float*)d_in[4];
  const float* Vh   = (const float*)d_in[5];
  const float* P    = (const float*)d_in[6];
  const float* gv   = (const float*)d_in[7];
  float* out = (float*)d_out;

  const size_t W_ELE = (size_t)N_TOT * K_TOT;   // 4,194,304
  const size_t X_ELE = (size_t)M_TOT * K_TOT;   // 33,554,432
  const size_t TILED_WS = (W_ELE + X_ELE) * 2 + (2 * M_TOT + 2 * N_TOT) * 4;

  if (ws_size >= TILED_WS) {
    unsigned short* Whi_t = (unsigned short*)d_ws;
    unsigned short* Xhi_t = Whi_t + W_ELE;
    float* T  = (float*)(Xhi_t + X_ELE);
    float* CU = T + 2 * M_TOT;

    wsplit_base<<<dim3(N_TOT), 256, 0, stream>>>(Wb, U, S, Vh, P, gv, Whi_t, CU);
    xsplit_tiled<<<dim3(M_TOT / 4), 256, 0, stream>>>(x, Vh, Xhi_t, T);
    gemm8_kernel<<<dim3((M_TOT / 256) * (N_TOT / 256)), 512, 0, stream>>>(
        Xhi_t, Whi_t, bias, T, CU, out);
  } else {
    unsigned short* Whi = (unsigned short*)d_ws;
    unsigned short* Wlo = Whi + W_ELE;
    wsplit_kernel<<<dim3((N_TOT * K_TOT / 4) / 256), 256, 0, stream>>>(
        Wb, U, S, Vh, P, gv, Whi, Wlo);
    gemm_split_kernel<<<dim3(N_TOT / 128, M_TOT / 128), 256, 0, stream>>>(
        x, Whi, Wlo, bias, out);
  }
}